// Round 11
// baseline (44.783 us; speedup 1.0000x reference)
//
#include <hip/hip_runtime.h>
#include <math.h>

#define N_NODES 4096
#define F_DIM   512
#define D_DIM   512   // H*d
#define H_HEADS 8
#define HD      64    // per-head out dim
#define CAP     128   // per-row neighbor cap (mean 42, sigma 6.4 -> 13 sigma)

typedef __attribute__((ext_vector_type(8))) short short8;
typedef __attribute__((ext_vector_type(4))) float f32x4;

__device__ __forceinline__ unsigned short f2bf(float f) {
    unsigned int u = __builtin_bit_cast(unsigned int, f);
    return (unsigned short)((u + 0x7FFFu + ((u >> 16) & 1u)) >> 16);   // RNE
}
__device__ __forceinline__ float bflo(unsigned int u) {
    return __builtin_bit_cast(float, u << 16);
}
__device__ __forceinline__ float bfhi(unsigned int u) {
    return __builtin_bit_cast(float, u & 0xffff0000u);
}

// ---------------- Kernel 0: W[H,F,d] -> Bt bf16 [n=h*64+dd][k=f] ------------
__global__ __launch_bounds__(256) void conv_w(const float* __restrict__ W,
                                              unsigned short* __restrict__ Bt) {
    const int t = blockIdx.x * 256 + threadIdx.x;   // 8 k's per thread
    const int n = t >> 6;
    const int kb = (t & 63) * 8;
    const int h = n >> 6, dd = n & 63;
    const float* src = W + (size_t)h * F_DIM * HD + dd;
    unsigned short o[8];
    #pragma unroll
    for (int q = 0; q < 8; ++q) o[q] = f2bf(src[(size_t)(kb + q) * HD]);
    *(uint4*)&Bt[(size_t)n * F_DIM + kb] = *(const uint4*)o;
}

// ---------------- Kernel 1: GEMM (blocks 0..511) + adj compaction (512..1535)
__global__ __launch_bounds__(256) void mega(const float* __restrict__ x,
                                            const unsigned short* __restrict__ Bt,
                                            const float* __restrict__ adj,
                                            const float* __restrict__ a1,
                                            const float* __restrict__ b1,
                                            const float* __restrict__ a2,
                                            const float* __restrict__ b2,
                                            unsigned short* __restrict__ seqb,
                                            float* __restrict__ f1t,
                                            float* __restrict__ f2t,
                                            unsigned short* __restrict__ rowIdx,
                                            int* __restrict__ cntArr) {
    __shared__ unsigned short As[64][40];
    __shared__ unsigned short Bs[64][40];
    __shared__ float sF[2][64][2];

    const int tid  = threadIdx.x;
    const int lane = tid & 63;
    const int w    = tid >> 6;

    if (blockIdx.x >= 512) {
        // ---------------- adj compaction ----------------
        const int r = (blockIdx.x - 512) * 4 + w;      // this wave's row
        const float* arow = adj + (size_t)r * N_NODES;

        f32x4 vq[16];
        #pragma unroll
        for (int q = 0; q < 16; ++q)
            vq[q] = *(const f32x4*)&arow[q * 256 + lane * 4];

        unsigned long long mask = 0ull;
        #pragma unroll
        for (int q = 0; q < 16; ++q) {
            if (vq[q].x != 0.0f) mask |= 1ull << (q * 4 + 0);
            if (vq[q].y != 0.0f) mask |= 1ull << (q * 4 + 1);
            if (vq[q].z != 0.0f) mask |= 1ull << (q * 4 + 2);
            if (vq[q].w != 0.0f) mask |= 1ull << (q * 4 + 3);
        }
        const int n_t = __popcll(mask);
        int incl = n_t;
        #pragma unroll
        for (int off = 1; off < 64; off <<= 1) {
            int u = __shfl_up(incl, off, 64);
            if (lane >= off) incl += u;
        }
        const int tot = __shfl(incl, 63, 64);
        int pos = incl - n_t;
        unsigned short* rbase = rowIdx + (size_t)r * CAP;
        while (mask) {
            const int bit = __builtin_ctzll(mask);
            mask &= mask - 1;
            const int col = ((bit >> 2) << 8) + (lane << 2) + (bit & 3);
            if (pos < CAP)
                __builtin_nontemporal_store((unsigned short)col, rbase + pos);
            ++pos;
        }
        if (lane == 0) cntArr[r] = tot;
        return;
    }

    // ---------------- GEMM ----------------
    const int wr   = w >> 1, wc = w & 1;      // wave covers 32x32
    const int i0   = (blockIdx.x & 63) * 64;
    const int h    = blockIdx.x >> 6;         // head == column block
    const int n0   = h * 64;

    const int ar = tid >> 2;                  // 0..63
    const int ac = (tid & 3) * 8;             // 0,8,16,24

    const int rlane = lane & 15;
    const int q     = lane >> 4;
    const int klane = q * 8;

    f32x4 acc[2][2] = {};

    for (int k0 = 0; k0 < F_DIM; k0 += 32) {
        const float* ga = &x[(size_t)(i0 + ar) * F_DIM + k0 + ac];
        const float4 xa = *(const float4*)ga;
        const float4 xb4 = *(const float4*)(ga + 4);
        unsigned short ao[8] = {f2bf(xa.x), f2bf(xa.y), f2bf(xa.z), f2bf(xa.w),
                                f2bf(xb4.x), f2bf(xb4.y), f2bf(xb4.z), f2bf(xb4.w)};
        const uint4 bv = *(const uint4*)&Bt[(size_t)(n0 + ar) * F_DIM + k0 + ac];
        __syncthreads();
        *(uint4*)&As[ar][ac] = *(const uint4*)ao;
        *(uint4*)&Bs[ar][ac] = bv;
        __syncthreads();

        short8 a_frag[2], b_frag[2];
        #pragma unroll
        for (int mi = 0; mi < 2; ++mi)
            a_frag[mi] = *(const short8*)&As[wr * 32 + mi * 16 + rlane][klane];
        #pragma unroll
        for (int ni = 0; ni < 2; ++ni)
            b_frag[ni] = *(const short8*)&Bs[wc * 32 + ni * 16 + rlane][klane];
        #pragma unroll
        for (int mi = 0; mi < 2; ++mi)
            #pragma unroll
            for (int ni = 0; ni < 2; ++ni)
                acc[mi][ni] = __builtin_amdgcn_mfma_f32_16x16x32_bf16(
                    a_frag[mi], b_frag[ni], acc[mi][ni], 0, 0, 0);
    }

    // ---- epilogue 1: store seqb (bf16) ----
    #pragma unroll
    for (int mi = 0; mi < 2; ++mi)
        #pragma unroll
        for (int ni = 0; ni < 2; ++ni)
            #pragma unroll
            for (int r = 0; r < 4; ++r) {
                const int row = i0 + wr * 32 + mi * 16 + q * 4 + r;
                const int col = n0 + wc * 32 + ni * 16 + rlane;
                seqb[(size_t)row * D_DIM + col] = f2bf(acc[mi][ni][r]);
            }

    // ---- epilogue 2: f1/f2 partial dots, transposed [N][8] output ----
    float a1v[2], a2v[2];
    #pragma unroll
    for (int ni = 0; ni < 2; ++ni) {
        const int c = wc * 32 + ni * 16 + rlane;
        a1v[ni] = a1[h * HD + c];
        a2v[ni] = a2[h * HD + c];
    }
    #pragma unroll
    for (int mi = 0; mi < 2; ++mi)
        #pragma unroll
        for (int r = 0; r < 4; ++r) {
            float s1 = acc[mi][0][r] * a1v[0] + acc[mi][1][r] * a1v[1];
            float s2 = acc[mi][0][r] * a2v[0] + acc[mi][1][r] * a2v[1];
            #pragma unroll
            for (int m = 1; m < 16; m <<= 1) {
                s1 += __shfl_xor(s1, m, 64);
                s2 += __shfl_xor(s2, m, 64);
            }
            if (rlane == 0) {
                const int rl = wr * 32 + mi * 16 + q * 4 + r;
                sF[0][rl][wc] = s1;
                sF[1][rl][wc] = s2;
            }
        }
    __syncthreads();
    if (tid < 64) {
        const int row = i0 + tid;
        f1t[row * 8 + h] = sF[0][tid][0] + sF[0][tid][1] + b1[h];
        f2t[row * 8 + h] = sF[1][tid][0] + sF[1][tid][1] + b2[h];
    }
}

// ---------------- Kernel 2: attn v3 — feature-split, L2-resident gather -----
// 8192 blocks x 64 threads: block = (row i, half). half h covers features
// [h*256, h*256+256) = heads [h*4, h*4+4). Active gather set per phase = 2 MB
// (fits each XCD L2). Lane covers 4 features (dwordx2 gather).
__global__ __launch_bounds__(64) void attn(const float* __restrict__ adj,
                                           const unsigned short* __restrict__ seqb,
                                           const float* __restrict__ f1t,
                                           const float* __restrict__ f2t,
                                           const unsigned short* __restrict__ rowIdx,
                                           const int* __restrict__ cntArr,
                                           float* __restrict__ out) {
    __shared__ int   sIdx[CAP];      // zero-padded
    __shared__ float sP[CAP][4];     // zero-padded numerators (4 heads)

    const int bid  = blockIdx.x;
    const int half = bid >> 12;      // 0..1 (all half-0 blocks dispatch first)
    const int i    = bid & (N_NODES - 1);
    const int lane = threadIdx.x;
    const int hq   = lane >> 4;      // head-quarter 0..3 within this half

    const int cnt = cntArr[i];

    // f1 for this row's 4 heads of this half
    const float4 f1h4 = *(const float4*)&f1t[i * 8 + half * 4];
    const float f1r[4] = {f1h4.x, f1h4.y, f1h4.z, f1h4.w};

    float accv[4] = {0.f, 0.f, 0.f, 0.f};
    float myinv;

    if (cnt <= CAP) {
        // ---- numerators in registers (<=2 neighbors/thread) ----
        int j0 = 0, j1 = 0;
        float e0[4] = {0.f, 0.f, 0.f, 0.f};
        float e1[4] = {0.f, 0.f, 0.f, 0.f};
        const bool has0 = lane < cnt;
        const bool has1 = lane + 64 < cnt;
        if (has0) {
            j0 = (int)rowIdx[(size_t)i * CAP + lane];
            const float4 fv = *(const float4*)&f2t[j0 * 8 + half * 4];
            const float f2r[4] = {fv.x, fv.y, fv.z, fv.w};
            #pragma unroll
            for (int h = 0; h < 4; ++h) {
                float v = f1r[h] + f2r[h];
                v = fmaxf(v, 0.2f * v);
                e0[h] = __expf(v);           // |logit| small: no max-sub needed
            }
        }
        if (has1) {
            j1 = (int)rowIdx[(size_t)i * CAP + lane + 64];
            const float4 fv = *(const float4*)&f2t[j1 * 8 + half * 4];
            const float f2r[4] = {fv.x, fv.y, fv.z, fv.w};
            #pragma unroll
            for (int h = 0; h < 4; ++h) {
                float v = f1r[h] + f2r[h];
                v = fmaxf(v, 0.2f * v);
                e1[h] = __expf(v);
            }
        }
        sIdx[lane]      = j0;                // 0 for pad
        sIdx[lane + 64] = j1;
        f32x4 ea = {e0[0], e0[1], e0[2], e0[3]};
        f32x4 eb = {e1[0], e1[1], e1[2], e1[3]};
        *(f32x4*)&sP[lane][0]      = ea;     // 0 for pad
        *(f32x4*)&sP[lane + 64][0] = eb;

        float s[4];
        #pragma unroll
        for (int h = 0; h < 4; ++h) s[h] = e0[h] + e1[h];
        #pragma unroll
        for (int off = 32; off; off >>= 1)
            #pragma unroll
            for (int h = 0; h < 4; ++h)
                s[h] += __shfl_xor(s[h], off, 64);
        myinv = 1.0f;
        #pragma unroll
        for (int h = 0; h < 4; ++h)
            if (h == hq) myinv = 1.0f / s[h];
        __syncthreads();                     // publishes sIdx, sP

        // ---- aggregation: groups of 4 (pads contribute 0) ----
        const char* __restrict__ vbase =
            (const char*)seqb + half * 512 + lane * 8;
        const int G = (cnt + 3) >> 2;
        for (int g = 0; g < G; ++g) {
            const int4  j4 = *(const int4*)&sIdx[g * 4];
            const float p0 = sP[g * 4 + 0][hq];
            const float p1 = sP[g * 4 + 1][hq];
            const float p2 = sP[g * 4 + 2][hq];
            const float p3 = sP[g * 4 + 3][hq];
            const uint2 u0 = *(const uint2*)(vbase + ((size_t)j4.x << 10));
            const uint2 u1 = *(const uint2*)(vbase + ((size_t)j4.y << 10));
            const uint2 u2 = *(const uint2*)(vbase + ((size_t)j4.z << 10));
            const uint2 u3 = *(const uint2*)(vbase + ((size_t)j4.w << 10));
            accv[0] = fmaf(p0, bflo(u0.x), accv[0]);
            accv[1] = fmaf(p0, bfhi(u0.x), accv[1]);
            accv[2] = fmaf(p0, bflo(u0.y), accv[2]);
            accv[3] = fmaf(p0, bfhi(u0.y), accv[3]);
            accv[0] = fmaf(p1, bflo(u1.x), accv[0]);
            accv[1] = fmaf(p1, bfhi(u1.x), accv[1]);
            accv[2] = fmaf(p1, bflo(u1.y), accv[2]);
            accv[3] = fmaf(p1, bfhi(u1.y), accv[3]);
            accv[0] = fmaf(p2, bflo(u2.x), accv[0]);
            accv[1] = fmaf(p2, bfhi(u2.x), accv[1]);
            accv[2] = fmaf(p2, bflo(u2.y), accv[2]);
            accv[3] = fmaf(p2, bfhi(u2.y), accv[3]);
            accv[0] = fmaf(p3, bflo(u3.x), accv[0]);
            accv[1] = fmaf(p3, bfhi(u3.x), accv[1]);
            accv[2] = fmaf(p3, bflo(u3.y), accv[2]);
            accv[3] = fmaf(p3, bfhi(u3.y), accv[3]);
        }
    } else {
        // ---- fallback (cnt > CAP): stream adj; statistically never hit ----
        const float* arow = adj + (size_t)i * N_NODES;
        float s[4] = {0.f, 0.f, 0.f, 0.f};
        for (int jx = lane; jx < N_NODES; jx += 64) {
            if (arow[jx] != 0.0f) {
                const float4 fv = *(const float4*)&f2t[jx * 8 + half * 4];
                const float f2r[4] = {fv.x, fv.y, fv.z, fv.w};
                #pragma unroll
                for (int h = 0; h < 4; ++h) {
                    float v = f1r[h] + f2r[h];
                    v = fmaxf(v, 0.2f * v);
                    s[h] += __expf(v);
                }
            }
        }
        #pragma unroll
        for (int off = 32; off; off >>= 1)
            #pragma unroll
            for (int h = 0; h < 4; ++h)
                s[h] += __shfl_xor(s[h], off, 64);
        myinv = 1.0f;
        #pragma unroll
        for (int h = 0; h < 4; ++h)
            if (h == hq) myinv = 1.0f / s[h];
        const float f1h = f1r[hq];

        const char* __restrict__ vbase =
            (const char*)seqb + half * 512 + lane * 8;
        for (int jx = 0; jx < N_NODES; ++jx) {
            if (arow[jx] != 0.0f) {
                float v = f1h + f2t[jx * 8 + half * 4 + hq];
                v = fmaxf(v, 0.2f * v);
                const float p = __expf(v);
                const uint2 u = *(const uint2*)(vbase + ((size_t)jx << 10));
                accv[0] = fmaf(p, bflo(u.x), accv[0]);
                accv[1] = fmaf(p, bfhi(u.x), accv[1]);
                accv[2] = fmaf(p, bflo(u.y), accv[2]);
                accv[3] = fmaf(p, bfhi(u.y), accv[3]);
            }
        }
    }

    // ---- epilogue: scale, ELU, store (lane's 4 features, coalesced) ----
    float o[4];
    #pragma unroll
    for (int k = 0; k < 4; ++k) {
        const float v = accv[k] * myinv;
        o[k] = (v > 0.f) ? v : expm1f(v);
    }
    f32x4 ov = {o[0], o[1], o[2], o[3]};
    float* dst = &out[(size_t)i * D_DIM + half * 256 + lane * 4];
    __builtin_nontemporal_store(ov, (f32x4*)dst);
}

// ---------------- launch ----------------------------------------------------
extern "C" void kernel_launch(void* const* d_in, const int* in_sizes, int n_in,
                              void* d_out, int out_size, void* d_ws, size_t ws_size,
                              hipStream_t stream) {
    const float* x   = (const float*)d_in[0];
    const float* adj = (const float*)d_in[1];
    const float* W   = (const float*)d_in[2];
    const float* a1  = (const float*)d_in[3];
    const float* b1  = (const float*)d_in[4];
    const float* a2  = (const float*)d_in[5];
    const float* b2  = (const float*)d_in[6];
    float* out = (float*)d_out;

    char* ws = (char*)d_ws;
    unsigned short* seqb = (unsigned short*)ws;                                   // 4 MB
    unsigned short* Bt   = (unsigned short*)(ws + (size_t)N_NODES * D_DIM * 2);   // 0.5 MB
    float* f1t = (float*)(ws + (size_t)N_NODES * D_DIM * 2 + (size_t)D_DIM * F_DIM * 2);
    float* f2t = f1t + (size_t)N_NODES * H_HEADS;
    unsigned short* rowIdx = (unsigned short*)(f2t + (size_t)N_NODES * H_HEADS); // 1 MB
    int* cntArr = (int*)(rowIdx + (size_t)N_NODES * CAP);                        // 16 KB

    conv_w<<<128, 256, 0, stream>>>(W, Bt);

    mega<<<1536, 256, 0, stream>>>(x, Bt, adj, a1, b1, a2, b2,
                                   seqb, f1t, f2t, rowIdx, cntArr);

    attn<<<2 * N_NODES, 64, 0, stream>>>(adj, seqb, f1t, f2t, rowIdx, cntArr, out);
}